// Round 1
// baseline (6139.675 us; speedup 1.0000x reference)
//
#include <hip/hip_runtime.h>
#include <hip/hip_bf16.h>

#define HID 128
#define NGRAPH 512
#define IN_DIM 384

// ---------------- degree / norm ----------------
__global__ void deg_kernel(const int* __restrict__ dst, int* __restrict__ deg, int E) {
    int e = blockIdx.x * blockDim.x + threadIdx.x;
    if (e < E) atomicAdd(&deg[dst[e]], 1);
}

__global__ void dis_kernel(const int* __restrict__ deg, float* __restrict__ dis, int n) {
    int v = blockIdx.x * blockDim.x + threadIdx.x;
    if (v < n) dis[v] = rsqrtf((float)(deg[v] + 1));  // +1 = self-loop
}

// ---------------- GEMM with row-scale epilogue: out[v,:] = (X[v,:] @ W) * dis[v] ----------------
// 8 rows per block, 256 threads: thread t -> row t>>5, cols 4*(t&31)..+3
template <int K>
__global__ __launch_bounds__(256) void gemm_scale(const float* __restrict__ X,
                                                  const float* __restrict__ W,
                                                  const float* __restrict__ dis,
                                                  float* __restrict__ out) {
    __shared__ float xs[8 * K];
    const int b = blockIdx.x, t = threadIdx.x;
    const long base = (long)b * 8 * K;
    for (int i = t; i < 8 * K; i += 256) xs[i] = X[base + i];
    __syncthreads();
    const int r = t >> 5, c = (t & 31) << 2;
    const float* xr = &xs[r * K];
    float4 acc = make_float4(0.f, 0.f, 0.f, 0.f);
#pragma unroll 4
    for (int k = 0; k < K; k++) {
        const float xv = xr[k];
        const float4 w = *(const float4*)&W[k * HID + c];
        acc.x = fmaf(xv, w.x, acc.x);
        acc.y = fmaf(xv, w.y, acc.y);
        acc.z = fmaf(xv, w.z, acc.z);
        acc.w = fmaf(xv, w.w, acc.w);
    }
    const int v = b * 8 + r;
    const float dv = dis[v];
    acc.x *= dv; acc.y *= dv; acc.z *= dv; acc.w *= dv;
    *(float4*)&out[(long)v * HID + c] = acc;
}

// ---------------- edge scatter: agg[d,:] += hs[s,:] ----------------
// 32 threads per edge, float4 each
__global__ __launch_bounds__(256) void scatter_kernel(const float* __restrict__ hs,
                                                      const int* __restrict__ src,
                                                      const int* __restrict__ dst,
                                                      float* __restrict__ agg, int E) {
    const long gid = (long)blockIdx.x * blockDim.x + threadIdx.x;
    const int e = (int)(gid >> 5);
    if (e >= E) return;
    const int c = ((int)gid & 31) << 2;
    const int s = src[e], d = dst[e];
    const float4 m = *(const float4*)&hs[(long)s * HID + c];
    float* p = &agg[(long)d * HID + c];
    unsafeAtomicAdd(p + 0, m.x);
    unsafeAtomicAdd(p + 1, m.y);
    unsafeAtomicAdd(p + 2, m.z);
    unsafeAtomicAdd(p + 3, m.w);
}

// ---------------- finalize (in place over agg): h = relu(dis*(agg + hs) + b) ----------------
__global__ __launch_bounds__(256) void finalize_kernel(float* __restrict__ agg,
                                                       const float* __restrict__ hs,
                                                       const float* __restrict__ dis,
                                                       const float* __restrict__ bias, int n) {
    const long gid = (long)blockIdx.x * blockDim.x + threadIdx.x;
    const int v = (int)(gid >> 5);
    if (v >= n) return;
    const int c = ((int)gid & 31) << 2;
    const float4 a = *(const float4*)&agg[(long)v * HID + c];
    const float4 h = *(const float4*)&hs[(long)v * HID + c];
    const float4 bb = *(const float4*)&bias[c];
    const float dv = dis[v];
    float4 r;
    r.x = fmaxf(fmaf(dv, a.x + h.x, bb.x), 0.f);
    r.y = fmaxf(fmaf(dv, a.y + h.y, bb.y), 0.f);
    r.z = fmaxf(fmaf(dv, a.z + h.z, bb.z), 0.f);
    r.w = fmaxf(fmaf(dv, a.w + h.w, bb.w), 0.f);
    *(float4*)&agg[(long)v * HID + c] = r;
}

// ---------------- pooling: sums[g,:] += h[v,:], cnt[g]++ ----------------
__global__ __launch_bounds__(256) void pool_kernel(const float* __restrict__ h,
                                                   const int* __restrict__ batch,
                                                   float* __restrict__ sums,
                                                   int* __restrict__ cnt, int n) {
    const long gid = (long)blockIdx.x * blockDim.x + threadIdx.x;
    const int v = (int)(gid >> 5);
    if (v >= n) return;
    const int c = ((int)gid & 31) << 2;
    const int g = batch[v];
    const float4 x = *(const float4*)&h[(long)v * HID + c];
    float* p = &sums[g * HID + c];
    unsafeAtomicAdd(p + 0, x.x);
    unsafeAtomicAdd(p + 1, x.y);
    unsafeAtomicAdd(p + 2, x.z);
    unsafeAtomicAdd(p + 3, x.w);
    if (c == 0) atomicAdd(&cnt[g], 1);
}

// ---------------- mean + MLP head: out = sigmoid(relu(mean @ Wl1 + bl1) @ Wl2 + bl2) ----------------
__global__ __launch_bounds__(64) void mlp_kernel(const float* __restrict__ sums,
                                                 const int* __restrict__ cnt,
                                                 const float* __restrict__ Wl1,
                                                 const float* __restrict__ bl1,
                                                 const float* __restrict__ Wl2,
                                                 const float* __restrict__ bl2,
                                                 float* __restrict__ out) {
    const int g = blockIdx.x, t = threadIdx.x;  // 64 threads
    __shared__ float mean[HID];
    __shared__ float hid[64];
    const float c = fmaxf((float)cnt[g], 1.0f);
    mean[t] = sums[g * HID + t] / c;
    mean[t + 64] = sums[g * HID + 64 + t] / c;
    __syncthreads();
    float acc = bl1[t];
#pragma unroll 4
    for (int k = 0; k < HID; k++) acc = fmaf(mean[k], Wl1[k * 64 + t], acc);
    hid[t] = fmaxf(acc, 0.f);
    __syncthreads();
    if (t < 5) {
        float a = bl2[t];
#pragma unroll 4
        for (int k = 0; k < 64; k++) a = fmaf(hid[k], Wl2[k * 5 + t], a);
        out[g * 5 + t] = 1.f / (1.f + expf(-a));
    }
}

extern "C" void kernel_launch(void* const* d_in, const int* in_sizes, int n_in,
                              void* d_out, int out_size, void* d_ws, size_t ws_size,
                              hipStream_t stream) {
    const float* x   = (const float*)d_in[0];
    const int* ei    = (const int*)d_in[1];
    const int* batch = (const int*)d_in[2];
    const float* W1  = (const float*)d_in[3];
    const float* b1  = (const float*)d_in[4];
    const float* W2  = (const float*)d_in[5];
    const float* b2  = (const float*)d_in[6];
    const float* Wl1 = (const float*)d_in[7];
    const float* bl1 = (const float*)d_in[8];
    const float* Wl2 = (const float*)d_in[9];
    const float* bl2 = (const float*)d_in[10];
    float* out = (float*)d_out;

    const int n = in_sizes[0] / IN_DIM;       // 50000
    const int E = in_sizes[1] / 2;            // 1600000
    const int* src = ei;
    const int* dst = ei + E;

    // workspace layout (256B aligned)
    char* ws = (char*)d_ws;
    size_t off = 0;
    auto alloc = [&](size_t bytes) {
        void* p = ws + off;
        off = (off + bytes + 255) & ~(size_t)255;
        return p;
    };
    int*   deg  = (int*)alloc((size_t)n * 4);
    float* dis  = (float*)alloc((size_t)n * 4);
    float* buf0 = (float*)alloc((size_t)n * HID * 4);   // hs (scaled GEMM out)
    float* buf1 = (float*)alloc((size_t)n * HID * 4);   // agg -> h (in place)
    float* sums = (float*)alloc((size_t)NGRAPH * HID * 4);
    int*   cnt  = (int*)alloc((size_t)NGRAPH * 4);
    (void)ws_size;

    const int nodeBlocks  = (n * 32 + 255) / 256;       // node x 32-lane kernels
    const int edgeBlocks  = (int)(((long)E * 32 + 255) / 256);
    const int gemmBlocks  = (n + 7) / 8;

    // --- degree / norm ---
    hipMemsetAsync(deg, 0, (size_t)n * 4, stream);
    deg_kernel<<<(E + 255) / 256, 256, 0, stream>>>(dst, deg, E);
    dis_kernel<<<(n + 255) / 256, 256, 0, stream>>>(deg, dis, n);

    // --- conv1 ---
    gemm_scale<IN_DIM><<<gemmBlocks, 256, 0, stream>>>(x, W1, dis, buf0);
    hipMemsetAsync(buf1, 0, (size_t)n * HID * 4, stream);
    scatter_kernel<<<edgeBlocks, 256, 0, stream>>>(buf0, src, dst, buf1, E);
    finalize_kernel<<<nodeBlocks, 256, 0, stream>>>(buf1, buf0, dis, b1, n);

    // --- conv2 ---
    gemm_scale<HID><<<gemmBlocks, 256, 0, stream>>>(buf1, W2, dis, buf0);
    hipMemsetAsync(buf1, 0, (size_t)n * HID * 4, stream);
    scatter_kernel<<<edgeBlocks, 256, 0, stream>>>(buf0, src, dst, buf1, E);
    finalize_kernel<<<nodeBlocks, 256, 0, stream>>>(buf1, buf0, dis, b2, n);

    // --- pool + head ---
    hipMemsetAsync(sums, 0, (size_t)NGRAPH * HID * 4, stream);
    hipMemsetAsync(cnt, 0, (size_t)NGRAPH * 4, stream);
    pool_kernel<<<nodeBlocks, 256, 0, stream>>>(buf1, batch, sums, cnt, n);
    mlp_kernel<<<NGRAPH, 64, 0, stream>>>(sums, cnt, Wl1, bl1, Wl2, bl2, out);
}

// Round 2
// 1066.009 us; speedup vs baseline: 5.7595x; 5.7595x over previous
//
#include <hip/hip_runtime.h>
#include <hip/hip_bf16.h>

#define HID 128
#define NGRAPH 512
#define IN_DIM 384

// ---------------- degree ----------------
__global__ void deg_kernel(const int* __restrict__ dst, int* __restrict__ deg, int E) {
    int e = blockIdx.x * blockDim.x + threadIdx.x;
    if (e < E) atomicAdd(&deg[dst[e]], 1);
}

__global__ void dis_kernel(const int* __restrict__ deg, float* __restrict__ dis, int n) {
    int v = blockIdx.x * blockDim.x + threadIdx.x;
    if (v < n) dis[v] = rsqrtf((float)(deg[v] + 1));  // +1 = self-loop
}

// ---------------- exclusive scan of deg -> row_start (3-kernel scan, chunk=1024) ----------------
__global__ __launch_bounds__(256) void scan_part(const int* __restrict__ deg, int* __restrict__ row,
                                                 int* __restrict__ blockSums, int n) {
    __shared__ int ts[256];
    const int b = blockIdx.x, t = threadIdx.x;
    const int base = b * 1024 + t * 4;
    int v0 = (base + 0 < n) ? deg[base + 0] : 0;
    int v1 = (base + 1 < n) ? deg[base + 1] : 0;
    int v2 = (base + 2 < n) ? deg[base + 2] : 0;
    int v3 = (base + 3 < n) ? deg[base + 3] : 0;
    const int s = v0 + v1 + v2 + v3;
    ts[t] = s;
    __syncthreads();
    for (int off = 1; off < 256; off <<= 1) {
        int x = (t >= off) ? ts[t - off] : 0;
        __syncthreads();
        ts[t] += x;
        __syncthreads();
    }
    int p = ts[t] - s;  // exclusive prefix of this thread within block
    if (base + 0 < n) { row[base + 0] = p; p += v0; }
    if (base + 1 < n) { row[base + 1] = p; p += v1; }
    if (base + 2 < n) { row[base + 2] = p; p += v2; }
    if (base + 3 < n) { row[base + 3] = p; }
    if (t == 255) blockSums[b] = ts[255];
}

__global__ void scan_tops(int* __restrict__ blockSums, int nb) {
    if (threadIdx.x == 0 && blockIdx.x == 0) {
        int acc = 0;
        for (int i = 0; i < nb; i++) { int v = blockSums[i]; blockSums[i] = acc; acc += v; }
    }
}

__global__ __launch_bounds__(256) void scan_add(int* __restrict__ row, int* __restrict__ cursor,
                                                const int* __restrict__ blockSums, int n, int E) {
    const int b = blockIdx.x, t = threadIdx.x;
    const int off = blockSums[b];
    const int base = b * 1024 + t * 4;
#pragma unroll
    for (int j = 0; j < 4; j++) {
        int i = base + j;
        if (i < n) { int v = row[i] + off; row[i] = v; cursor[i] = v; }
    }
    if (b == 0 && t == 0) row[n] = E;
}

// ---------------- CSR fill: csr_src grouped by dst ----------------
__global__ void fill_kernel(const int* __restrict__ src, const int* __restrict__ dst,
                            int* __restrict__ cursor, int* __restrict__ csr_src, int E) {
    int e = blockIdx.x * blockDim.x + threadIdx.x;
    if (e < E) {
        int pos = atomicAdd(&cursor[dst[e]], 1);
        csr_src[pos] = src[e];
    }
}

// ---------------- GEMM with row-scale epilogue: out[v,:] = (X[v,:] @ W) * dis[v] ----------------
template <int K>
__global__ __launch_bounds__(256) void gemm_scale(const float* __restrict__ X,
                                                  const float* __restrict__ W,
                                                  const float* __restrict__ dis,
                                                  float* __restrict__ out) {
    __shared__ float xs[8 * K];
    const int b = blockIdx.x, t = threadIdx.x;
    const long base = (long)b * 8 * K;
    for (int i = t; i < 8 * K; i += 256) xs[i] = X[base + i];
    __syncthreads();
    const int r = t >> 5, c = (t & 31) << 2;
    const float* xr = &xs[r * K];
    float4 acc = make_float4(0.f, 0.f, 0.f, 0.f);
#pragma unroll 4
    for (int k = 0; k < K; k++) {
        const float xv = xr[k];
        const float4 w = *(const float4*)&W[k * HID + c];
        acc.x = fmaf(xv, w.x, acc.x);
        acc.y = fmaf(xv, w.y, acc.y);
        acc.z = fmaf(xv, w.z, acc.z);
        acc.w = fmaf(xv, w.w, acc.w);
    }
    const int v = b * 8 + r;
    const float dv = dis[v];
    acc.x *= dv; acc.y *= dv; acc.z *= dv; acc.w *= dv;
    *(float4*)&out[(long)v * HID + c] = acc;
}

// ---------------- gather aggregation + finalize (+ optional fused pool) ----------------
// One 64-lane wave per dst node; lane l covers cols 2l, 2l+1.
// h[v] = relu(dis[v] * (sum_{s->v} hs[s] + hs[v]) + bias)
template <bool POOL>
__global__ __launch_bounds__(256) void agg_kernel(const float* __restrict__ hs,
                                                  const int* __restrict__ csr_src,
                                                  const int* __restrict__ row,
                                                  const float* __restrict__ dis,
                                                  const float* __restrict__ bias,
                                                  const int* __restrict__ batch,
                                                  float* __restrict__ out,
                                                  float* __restrict__ sums,
                                                  int* __restrict__ cnt, int n) {
    const int v = blockIdx.x * 4 + (threadIdx.x >> 6);
    if (v >= n) return;
    const int lane = threadIdx.x & 63;
    const int c = lane << 1;
    int i = row[v];
    const int re = row[v + 1];
    float ax = 0.f, ay = 0.f, bx = 0.f, by = 0.f;
    for (; i + 1 < re; i += 2) {
        const int s0 = csr_src[i], s1 = csr_src[i + 1];
        const float2 m0 = *(const float2*)&hs[(long)s0 * HID + c];
        const float2 m1 = *(const float2*)&hs[(long)s1 * HID + c];
        ax += m0.x; ay += m0.y;
        bx += m1.x; by += m1.y;
    }
    if (i < re) {
        const int s = csr_src[i];
        const float2 m = *(const float2*)&hs[(long)s * HID + c];
        ax += m.x; ay += m.y;
    }
    const float2 self = *(const float2*)&hs[(long)v * HID + c];
    const float dv = dis[v];
    const float rx = fmaxf(fmaf(dv, ax + bx + self.x, bias[c]), 0.f);
    const float ry = fmaxf(fmaf(dv, ay + by + self.y, bias[c + 1]), 0.f);
    if (POOL) {
        const int g = batch[v];
        unsafeAtomicAdd(&sums[g * HID + c], rx);
        unsafeAtomicAdd(&sums[g * HID + c + 1], ry);
        if (lane == 0) atomicAdd(&cnt[g], 1);
    } else {
        float2 r; r.x = rx; r.y = ry;
        *(float2*)&out[(long)v * HID + c] = r;
    }
}

// ---------------- mean + MLP head ----------------
__global__ __launch_bounds__(64) void mlp_kernel(const float* __restrict__ sums,
                                                 const int* __restrict__ cnt,
                                                 const float* __restrict__ Wl1,
                                                 const float* __restrict__ bl1,
                                                 const float* __restrict__ Wl2,
                                                 const float* __restrict__ bl2,
                                                 float* __restrict__ out) {
    const int g = blockIdx.x, t = threadIdx.x;
    __shared__ float mean[HID];
    __shared__ float hid[64];
    const float c = fmaxf((float)cnt[g], 1.0f);
    mean[t] = sums[g * HID + t] / c;
    mean[t + 64] = sums[g * HID + 64 + t] / c;
    __syncthreads();
    float acc = bl1[t];
#pragma unroll 4
    for (int k = 0; k < HID; k++) acc = fmaf(mean[k], Wl1[k * 64 + t], acc);
    hid[t] = fmaxf(acc, 0.f);
    __syncthreads();
    if (t < 5) {
        float a = bl2[t];
#pragma unroll 4
        for (int k = 0; k < 64; k++) a = fmaf(hid[k], Wl2[k * 5 + t], a);
        out[g * 5 + t] = 1.f / (1.f + expf(-a));
    }
}

extern "C" void kernel_launch(void* const* d_in, const int* in_sizes, int n_in,
                              void* d_out, int out_size, void* d_ws, size_t ws_size,
                              hipStream_t stream) {
    const float* x   = (const float*)d_in[0];
    const int* ei    = (const int*)d_in[1];
    const int* batch = (const int*)d_in[2];
    const float* W1  = (const float*)d_in[3];
    const float* b1  = (const float*)d_in[4];
    const float* W2  = (const float*)d_in[5];
    const float* b2  = (const float*)d_in[6];
    const float* Wl1 = (const float*)d_in[7];
    const float* bl1 = (const float*)d_in[8];
    const float* Wl2 = (const float*)d_in[9];
    const float* bl2 = (const float*)d_in[10];
    float* out = (float*)d_out;

    const int n = in_sizes[0] / IN_DIM;       // 50000
    const int E = in_sizes[1] / 2;            // 1600000
    const int* src = ei;
    const int* dst = ei + E;

    char* ws = (char*)d_ws;
    size_t off = 0;
    auto alloc = [&](size_t bytes) {
        void* p = ws + off;
        off = (off + bytes + 255) & ~(size_t)255;
        return p;
    };
    int*   deg       = (int*)alloc((size_t)n * 4);
    float* dis       = (float*)alloc((size_t)n * 4);
    int*   row       = (int*)alloc((size_t)(n + 1) * 4);
    int*   cursor    = (int*)alloc((size_t)n * 4);
    int*   csr_src   = (int*)alloc((size_t)E * 4);
    int*   blockSums = (int*)alloc(256 * 4);
    float* buf0 = (float*)alloc((size_t)n * HID * 4);
    float* buf1 = (float*)alloc((size_t)n * HID * 4);
    float* sums = (float*)alloc((size_t)NGRAPH * HID * 4);
    int*   cnt  = (int*)alloc((size_t)NGRAPH * 4);
    (void)ws_size;

    const int nb = (n + 1023) / 1024;         // scan blocks
    const int gemmBlocks = (n + 7) / 8;
    const int aggBlocks  = (n + 3) / 4;

    // --- degree / norm / CSR ---
    hipMemsetAsync(deg, 0, (size_t)n * 4, stream);
    deg_kernel<<<(E + 255) / 256, 256, 0, stream>>>(dst, deg, E);
    dis_kernel<<<(n + 255) / 256, 256, 0, stream>>>(deg, dis, n);
    scan_part<<<nb, 256, 0, stream>>>(deg, row, blockSums, n);
    scan_tops<<<1, 64, 0, stream>>>(blockSums, nb);
    scan_add<<<nb, 256, 0, stream>>>(row, cursor, blockSums, n, E);
    fill_kernel<<<(E + 255) / 256, 256, 0, stream>>>(src, dst, cursor, csr_src, E);

    // --- conv1 ---
    gemm_scale<IN_DIM><<<gemmBlocks, 256, 0, stream>>>(x, W1, dis, buf0);
    agg_kernel<false><<<aggBlocks, 256, 0, stream>>>(buf0, csr_src, row, dis, b1, batch,
                                                     buf1, nullptr, nullptr, n);

    // --- conv2 (pool fused into epilogue) ---
    gemm_scale<HID><<<gemmBlocks, 256, 0, stream>>>(buf1, W2, dis, buf0);
    hipMemsetAsync(sums, 0, (size_t)NGRAPH * HID * 4, stream);
    hipMemsetAsync(cnt, 0, (size_t)NGRAPH * 4, stream);
    agg_kernel<true><<<aggBlocks, 256, 0, stream>>>(buf0, csr_src, row, dis, b2, batch,
                                                    nullptr, sums, cnt, n);

    // --- head ---
    mlp_kernel<<<NGRAPH, 64, 0, stream>>>(sums, cnt, Wl1, bl1, Wl2, bl2, out);
}

// Round 3
// 779.181 us; speedup vs baseline: 7.8796x; 1.3681x over previous
//
#include <hip/hip_runtime.h>
#include <hip/hip_bf16.h>

#define HID 128
#define NGRAPH 512
#define IN_DIM 384

// ---------------- degree ----------------
__global__ void deg_kernel(const int* __restrict__ dst, int* __restrict__ deg, int E) {
    int e = blockIdx.x * blockDim.x + threadIdx.x;
    if (e < E) atomicAdd(&deg[dst[e]], 1);
}

__global__ void dis_kernel(const int* __restrict__ deg, float* __restrict__ dis, int n) {
    int v = blockIdx.x * blockDim.x + threadIdx.x;
    if (v < n) dis[v] = rsqrtf((float)(deg[v] + 1));  // +1 = self-loop
}

// ---------------- exclusive scan of deg -> row_start ----------------
__global__ __launch_bounds__(256) void scan_part(const int* __restrict__ deg, int* __restrict__ row,
                                                 int* __restrict__ blockSums, int n) {
    __shared__ int ts[256];
    const int b = blockIdx.x, t = threadIdx.x;
    const int base = b * 1024 + t * 4;
    int v0 = (base + 0 < n) ? deg[base + 0] : 0;
    int v1 = (base + 1 < n) ? deg[base + 1] : 0;
    int v2 = (base + 2 < n) ? deg[base + 2] : 0;
    int v3 = (base + 3 < n) ? deg[base + 3] : 0;
    const int s = v0 + v1 + v2 + v3;
    ts[t] = s;
    __syncthreads();
    for (int off = 1; off < 256; off <<= 1) {
        int x = (t >= off) ? ts[t - off] : 0;
        __syncthreads();
        ts[t] += x;
        __syncthreads();
    }
    int p = ts[t] - s;
    if (base + 0 < n) { row[base + 0] = p; p += v0; }
    if (base + 1 < n) { row[base + 1] = p; p += v1; }
    if (base + 2 < n) { row[base + 2] = p; p += v2; }
    if (base + 3 < n) { row[base + 3] = p; }
    if (t == 255) blockSums[b] = ts[255];
}

__global__ void scan_tops(int* __restrict__ blockSums, int nb) {
    if (threadIdx.x == 0 && blockIdx.x == 0) {
        int acc = 0;
        for (int i = 0; i < nb; i++) { int v = blockSums[i]; blockSums[i] = acc; acc += v; }
    }
}

__global__ __launch_bounds__(256) void scan_add(int* __restrict__ row, int* __restrict__ cursor,
                                                const int* __restrict__ blockSums, int n, int E) {
    const int b = blockIdx.x, t = threadIdx.x;
    const int off = blockSums[b];
    const int base = b * 1024 + t * 4;
#pragma unroll
    for (int j = 0; j < 4; j++) {
        int i = base + j;
        if (i < n) { int v = row[i] + off; row[i] = v; cursor[i] = v; }
    }
    if (b == 0 && t == 0) row[n] = E;
}

// ---------------- CSR fill ----------------
__global__ void fill_kernel(const int* __restrict__ src, const int* __restrict__ dst,
                            int* __restrict__ cursor, int* __restrict__ csr_src, int E) {
    int e = blockIdx.x * blockDim.x + threadIdx.x;
    if (e < E) {
        int pos = atomicAdd(&cursor[dst[e]], 1);
        csr_src[pos] = src[e];
    }
}

// ---------------- tiled register-blocked GEMM: out[v,:] = (X[v,:] @ W) * dis[v] ----------------
// 64 rows x 128 cols per block; 256 threads; each thread: 8 rows x 4 cols.
// A staged transposed in LDS [KC][68] (16B-aligned stride, low conflict);
// W chunk staged contiguous [KC][128].
template <int K>
__global__ __launch_bounds__(256) void gemm_tile(const float* __restrict__ X,
                                                 const float* __restrict__ W,
                                                 const float* __restrict__ dis,
                                                 float* __restrict__ out, int n) {
    constexpr int KC = 32;
    __shared__ float asT[KC][68];
    __shared__ float bs[KC * HID];
    const int t = threadIdx.x;
    const int tx = t & 31;   // col quad: cols tx*4..+3
    const int ty = t >> 5;   // row group: rows ty*8..+7
    const int row0 = blockIdx.x * 64;

    float4 acc[8];
#pragma unroll
    for (int j = 0; j < 8; j++) acc[j] = make_float4(0.f, 0.f, 0.f, 0.f);

    const int ar = t >> 3;       // A staging row within half (0..31)
    const int af = t & 7;        // A staging float4 index along K (0..7)

    for (int k0 = 0; k0 < K; k0 += KC) {
        // --- stage A (transposed) ---
#pragma unroll
        for (int half = 0; half < 2; half++) {
            const int r = ar + half * 32;
            const int gr = row0 + r;
            float4 a = make_float4(0.f, 0.f, 0.f, 0.f);
            if (gr < n) a = *(const float4*)&X[(long)gr * K + k0 + af * 4];
            asT[af * 4 + 0][r] = a.x;
            asT[af * 4 + 1][r] = a.y;
            asT[af * 4 + 2][r] = a.z;
            asT[af * 4 + 3][r] = a.w;
        }
        // --- stage B (contiguous 16 KB) ---
        {
            const float4* wp = (const float4*)&W[(long)k0 * HID];
            float4* bp = (float4*)bs;
#pragma unroll
            for (int i = 0; i < 4; i++) bp[t + i * 256] = wp[t + i * 256];
        }
        __syncthreads();
#pragma unroll 8
        for (int kk = 0; kk < KC; kk++) {
            const float4 a0 = *(const float4*)&asT[kk][ty * 8];
            const float4 a1 = *(const float4*)&asT[kk][ty * 8 + 4];
            const float4 b  = *(const float4*)&bs[kk * HID + tx * 4];
            acc[0].x = fmaf(a0.x, b.x, acc[0].x); acc[0].y = fmaf(a0.x, b.y, acc[0].y);
            acc[0].z = fmaf(a0.x, b.z, acc[0].z); acc[0].w = fmaf(a0.x, b.w, acc[0].w);
            acc[1].x = fmaf(a0.y, b.x, acc[1].x); acc[1].y = fmaf(a0.y, b.y, acc[1].y);
            acc[1].z = fmaf(a0.y, b.z, acc[1].z); acc[1].w = fmaf(a0.y, b.w, acc[1].w);
            acc[2].x = fmaf(a0.z, b.x, acc[2].x); acc[2].y = fmaf(a0.z, b.y, acc[2].y);
            acc[2].z = fmaf(a0.z, b.z, acc[2].z); acc[2].w = fmaf(a0.z, b.w, acc[2].w);
            acc[3].x = fmaf(a0.w, b.x, acc[3].x); acc[3].y = fmaf(a0.w, b.y, acc[3].y);
            acc[3].z = fmaf(a0.w, b.z, acc[3].z); acc[3].w = fmaf(a0.w, b.w, acc[3].w);
            acc[4].x = fmaf(a1.x, b.x, acc[4].x); acc[4].y = fmaf(a1.x, b.y, acc[4].y);
            acc[4].z = fmaf(a1.x, b.z, acc[4].z); acc[4].w = fmaf(a1.x, b.w, acc[4].w);
            acc[5].x = fmaf(a1.y, b.x, acc[5].x); acc[5].y = fmaf(a1.y, b.y, acc[5].y);
            acc[5].z = fmaf(a1.y, b.z, acc[5].z); acc[5].w = fmaf(a1.y, b.w, acc[5].w);
            acc[6].x = fmaf(a1.z, b.x, acc[6].x); acc[6].y = fmaf(a1.z, b.y, acc[6].y);
            acc[6].z = fmaf(a1.z, b.z, acc[6].z); acc[6].w = fmaf(a1.z, b.w, acc[6].w);
            acc[7].x = fmaf(a1.w, b.x, acc[7].x); acc[7].y = fmaf(a1.w, b.y, acc[7].y);
            acc[7].z = fmaf(a1.w, b.z, acc[7].z); acc[7].w = fmaf(a1.w, b.w, acc[7].w);
        }
        __syncthreads();
    }

#pragma unroll
    for (int j = 0; j < 8; j++) {
        const int v = row0 + ty * 8 + j;
        if (v < n) {
            const float dv = dis[v];
            float4 r;
            r.x = acc[j].x * dv; r.y = acc[j].y * dv;
            r.z = acc[j].z * dv; r.w = acc[j].w * dv;
            *(float4*)&out[(long)v * HID + tx * 4] = r;
        }
    }
}

// ---------------- gather aggregation + finalize (+ optional fused pool) ----------------
template <bool POOL>
__global__ __launch_bounds__(256) void agg_kernel(const float* __restrict__ hs,
                                                  const int* __restrict__ csr_src,
                                                  const int* __restrict__ row,
                                                  const float* __restrict__ dis,
                                                  const float* __restrict__ bias,
                                                  const int* __restrict__ batch,
                                                  float* __restrict__ out,
                                                  float* __restrict__ sums,
                                                  int* __restrict__ cnt, int n) {
    const int v = blockIdx.x * 4 + (threadIdx.x >> 6);
    if (v >= n) return;
    const int lane = threadIdx.x & 63;
    const int c = lane << 1;
    int i = row[v];
    const int re = row[v + 1];
    float ax = 0.f, ay = 0.f, bx = 0.f, by = 0.f;
    for (; i + 1 < re; i += 2) {
        const int s0 = csr_src[i], s1 = csr_src[i + 1];
        const float2 m0 = *(const float2*)&hs[(long)s0 * HID + c];
        const float2 m1 = *(const float2*)&hs[(long)s1 * HID + c];
        ax += m0.x; ay += m0.y;
        bx += m1.x; by += m1.y;
    }
    if (i < re) {
        const int s = csr_src[i];
        const float2 m = *(const float2*)&hs[(long)s * HID + c];
        ax += m.x; ay += m.y;
    }
    const float2 self = *(const float2*)&hs[(long)v * HID + c];
    const float dv = dis[v];
    const float rx = fmaxf(fmaf(dv, ax + bx + self.x, bias[c]), 0.f);
    const float ry = fmaxf(fmaf(dv, ay + by + self.y, bias[c + 1]), 0.f);
    if (POOL) {
        const int g = batch[v];
        unsafeAtomicAdd(&sums[g * HID + c], rx);
        unsafeAtomicAdd(&sums[g * HID + c + 1], ry);
        if (lane == 0) atomicAdd(&cnt[g], 1);
    } else {
        float2 r; r.x = rx; r.y = ry;
        *(float2*)&out[(long)v * HID + c] = r;
    }
}

// ---------------- mean + MLP head ----------------
__global__ __launch_bounds__(64) void mlp_kernel(const float* __restrict__ sums,
                                                 const int* __restrict__ cnt,
                                                 const float* __restrict__ Wl1,
                                                 const float* __restrict__ bl1,
                                                 const float* __restrict__ Wl2,
                                                 const float* __restrict__ bl2,
                                                 float* __restrict__ out) {
    const int g = blockIdx.x, t = threadIdx.x;
    __shared__ float mean[HID];
    __shared__ float hid[64];
    const float c = fmaxf((float)cnt[g], 1.0f);
    mean[t] = sums[g * HID + t] / c;
    mean[t + 64] = sums[g * HID + 64 + t] / c;
    __syncthreads();
    float acc = bl1[t];
#pragma unroll 4
    for (int k = 0; k < HID; k++) acc = fmaf(mean[k], Wl1[k * 64 + t], acc);
    hid[t] = fmaxf(acc, 0.f);
    __syncthreads();
    if (t < 5) {
        float a = bl2[t];
#pragma unroll 4
        for (int k = 0; k < 64; k++) a = fmaf(hid[k], Wl2[k * 5 + t], a);
        out[g * 5 + t] = 1.f / (1.f + expf(-a));
    }
}

extern "C" void kernel_launch(void* const* d_in, const int* in_sizes, int n_in,
                              void* d_out, int out_size, void* d_ws, size_t ws_size,
                              hipStream_t stream) {
    const float* x   = (const float*)d_in[0];
    const int* ei    = (const int*)d_in[1];
    const int* batch = (const int*)d_in[2];
    const float* W1  = (const float*)d_in[3];
    const float* b1  = (const float*)d_in[4];
    const float* W2  = (const float*)d_in[5];
    const float* b2  = (const float*)d_in[6];
    const float* Wl1 = (const float*)d_in[7];
    const float* bl1 = (const float*)d_in[8];
    const float* Wl2 = (const float*)d_in[9];
    const float* bl2 = (const float*)d_in[10];
    float* out = (float*)d_out;

    const int n = in_sizes[0] / IN_DIM;       // 50000
    const int E = in_sizes[1] / 2;            // 1600000
    const int* src = ei;
    const int* dst = ei + E;

    char* ws = (char*)d_ws;
    size_t off = 0;
    auto alloc = [&](size_t bytes) {
        void* p = ws + off;
        off = (off + bytes + 255) & ~(size_t)255;
        return p;
    };
    int*   deg       = (int*)alloc((size_t)n * 4);
    float* dis       = (float*)alloc((size_t)n * 4);
    int*   row       = (int*)alloc((size_t)(n + 1) * 4);
    int*   cursor    = (int*)alloc((size_t)n * 4);
    int*   csr_src   = (int*)alloc((size_t)E * 4);
    int*   blockSums = (int*)alloc(256 * 4);
    float* buf0 = (float*)alloc((size_t)n * HID * 4);
    float* buf1 = (float*)alloc((size_t)n * HID * 4);
    float* sums = (float*)alloc((size_t)NGRAPH * HID * 4);
    int*   cnt  = (int*)alloc((size_t)NGRAPH * 4);
    (void)ws_size;

    const int nb = (n + 1023) / 1024;
    const int gemmBlocks = (n + 63) / 64;
    const int aggBlocks  = (n + 3) / 4;

    // --- degree / norm / CSR ---
    hipMemsetAsync(deg, 0, (size_t)n * 4, stream);
    deg_kernel<<<(E + 255) / 256, 256, 0, stream>>>(dst, deg, E);
    dis_kernel<<<(n + 255) / 256, 256, 0, stream>>>(deg, dis, n);
    scan_part<<<nb, 256, 0, stream>>>(deg, row, blockSums, n);
    scan_tops<<<1, 64, 0, stream>>>(blockSums, nb);
    scan_add<<<nb, 256, 0, stream>>>(row, cursor, blockSums, n, E);
    fill_kernel<<<(E + 255) / 256, 256, 0, stream>>>(src, dst, cursor, csr_src, E);

    // --- conv1 ---
    gemm_tile<IN_DIM><<<gemmBlocks, 256, 0, stream>>>(x, W1, dis, buf0, n);
    agg_kernel<false><<<aggBlocks, 256, 0, stream>>>(buf0, csr_src, row, dis, b1, batch,
                                                     buf1, nullptr, nullptr, n);

    // --- conv2 (pool fused) ---
    gemm_tile<HID><<<gemmBlocks, 256, 0, stream>>>(buf1, W2, dis, buf0, n);
    hipMemsetAsync(sums, 0, (size_t)NGRAPH * HID * 4, stream);
    hipMemsetAsync(cnt, 0, (size_t)NGRAPH * 4, stream);
    agg_kernel<true><<<aggBlocks, 256, 0, stream>>>(buf0, csr_src, row, dis, b2, batch,
                                                    nullptr, sums, cnt, n);

    // --- head ---
    mlp_kernel<<<NGRAPH, 64, 0, stream>>>(sums, cnt, Wl1, bl1, Wl2, bl2, out);
}

// Round 4
// 635.407 us; speedup vs baseline: 9.6626x; 1.2263x over previous
//
#include <hip/hip_runtime.h>
#include <hip/hip_bf16.h>

#define HID 128
#define NGRAPH 512
#define IN_DIM 384

__device__ __forceinline__ float bf2f(unsigned int u16) {
    union { float f; unsigned int i; } x;
    x.i = u16 << 16;
    return x.f;
}
__device__ __forceinline__ unsigned short f2bf(float f) {
    union { float f; unsigned int i; } x;
    x.f = f;
    unsigned int r = (x.i + 0x7FFFu + ((x.i >> 16) & 1u)) >> 16;
    return (unsigned short)r;
}

// ---------------- degree ----------------
__global__ void deg_kernel(const int* __restrict__ dst, int* __restrict__ deg, int E) {
    int e = blockIdx.x * blockDim.x + threadIdx.x;
    if (e < E) atomicAdd(&deg[dst[e]], 1);
}

__global__ void dis_kernel(const int* __restrict__ deg, float* __restrict__ dis, int n) {
    int v = blockIdx.x * blockDim.x + threadIdx.x;
    if (v < n) dis[v] = rsqrtf((float)(deg[v] + 1));  // +1 = self-loop
}

// ---------------- exclusive scan of deg -> row_start ----------------
__global__ __launch_bounds__(256) void scan_part(const int* __restrict__ deg, int* __restrict__ row,
                                                 int* __restrict__ blockSums, int n) {
    __shared__ int ts[256];
    const int b = blockIdx.x, t = threadIdx.x;
    const int base = b * 1024 + t * 4;
    int v0 = (base + 0 < n) ? deg[base + 0] : 0;
    int v1 = (base + 1 < n) ? deg[base + 1] : 0;
    int v2 = (base + 2 < n) ? deg[base + 2] : 0;
    int v3 = (base + 3 < n) ? deg[base + 3] : 0;
    const int s = v0 + v1 + v2 + v3;
    ts[t] = s;
    __syncthreads();
    for (int off = 1; off < 256; off <<= 1) {
        int x = (t >= off) ? ts[t - off] : 0;
        __syncthreads();
        ts[t] += x;
        __syncthreads();
    }
    int p = ts[t] - s;
    if (base + 0 < n) { row[base + 0] = p; p += v0; }
    if (base + 1 < n) { row[base + 1] = p; p += v1; }
    if (base + 2 < n) { row[base + 2] = p; p += v2; }
    if (base + 3 < n) { row[base + 3] = p; }
    if (t == 255) blockSums[b] = ts[255];
}

__global__ void scan_tops(int* __restrict__ blockSums, int nb) {
    if (threadIdx.x == 0 && blockIdx.x == 0) {
        int acc = 0;
        for (int i = 0; i < nb; i++) { int v = blockSums[i]; blockSums[i] = acc; acc += v; }
    }
}

__global__ __launch_bounds__(256) void scan_add(int* __restrict__ row, int* __restrict__ cursor,
                                                const int* __restrict__ blockSums, int n, int E) {
    const int b = blockIdx.x, t = threadIdx.x;
    const int off = blockSums[b];
    const int base = b * 1024 + t * 4;
#pragma unroll
    for (int j = 0; j < 4; j++) {
        int i = base + j;
        if (i < n) { int v = row[i] + off; row[i] = v; cursor[i] = v; }
    }
    if (b == 0 && t == 0) row[n] = E;
}

// ---------------- CSR fill ----------------
__global__ void fill_kernel(const int* __restrict__ src, const int* __restrict__ dst,
                            int* __restrict__ cursor, int* __restrict__ csr_src, int E) {
    int e = blockIdx.x * blockDim.x + threadIdx.x;
    if (e < E) {
        int pos = atomicAdd(&cursor[dst[e]], 1);
        csr_src[pos] = src[e];
    }
}

// ---------------- tiled register-blocked GEMM: hsb[v,:] = bf16((X[v,:] @ W) * dis[v]) ------------
template <int K>
__global__ __launch_bounds__(256) void gemm_tile(const float* __restrict__ X,
                                                 const float* __restrict__ W,
                                                 const float* __restrict__ dis,
                                                 unsigned short* __restrict__ outb, int n) {
    constexpr int KC = 32;
    __shared__ float asT[KC][68];
    __shared__ float bs[KC * HID];
    const int t = threadIdx.x;
    const int tx = t & 31;   // col quad
    const int ty = t >> 5;   // row group
    const int row0 = blockIdx.x * 64;

    float4 acc[8];
#pragma unroll
    for (int j = 0; j < 8; j++) acc[j] = make_float4(0.f, 0.f, 0.f, 0.f);

    const int ar = t >> 3;
    const int af = t & 7;

    for (int k0 = 0; k0 < K; k0 += KC) {
#pragma unroll
        for (int half = 0; half < 2; half++) {
            const int r = ar + half * 32;
            const int gr = row0 + r;
            float4 a = make_float4(0.f, 0.f, 0.f, 0.f);
            if (gr < n) a = *(const float4*)&X[(long)gr * K + k0 + af * 4];
            asT[af * 4 + 0][r] = a.x;
            asT[af * 4 + 1][r] = a.y;
            asT[af * 4 + 2][r] = a.z;
            asT[af * 4 + 3][r] = a.w;
        }
        {
            const float4* wp = (const float4*)&W[(long)k0 * HID];
            float4* bp = (float4*)bs;
#pragma unroll
            for (int i = 0; i < 4; i++) bp[t + i * 256] = wp[t + i * 256];
        }
        __syncthreads();
#pragma unroll 8
        for (int kk = 0; kk < KC; kk++) {
            const float4 a0 = *(const float4*)&asT[kk][ty * 8];
            const float4 a1 = *(const float4*)&asT[kk][ty * 8 + 4];
            const float4 b  = *(const float4*)&bs[kk * HID + tx * 4];
            acc[0].x = fmaf(a0.x, b.x, acc[0].x); acc[0].y = fmaf(a0.x, b.y, acc[0].y);
            acc[0].z = fmaf(a0.x, b.z, acc[0].z); acc[0].w = fmaf(a0.x, b.w, acc[0].w);
            acc[1].x = fmaf(a0.y, b.x, acc[1].x); acc[1].y = fmaf(a0.y, b.y, acc[1].y);
            acc[1].z = fmaf(a0.y, b.z, acc[1].z); acc[1].w = fmaf(a0.y, b.w, acc[1].w);
            acc[2].x = fmaf(a0.z, b.x, acc[2].x); acc[2].y = fmaf(a0.z, b.y, acc[2].y);
            acc[2].z = fmaf(a0.z, b.z, acc[2].z); acc[2].w = fmaf(a0.z, b.w, acc[2].w);
            acc[3].x = fmaf(a0.w, b.x, acc[3].x); acc[3].y = fmaf(a0.w, b.y, acc[3].y);
            acc[3].z = fmaf(a0.w, b.z, acc[3].z); acc[3].w = fmaf(a0.w, b.w, acc[3].w);
            acc[4].x = fmaf(a1.x, b.x, acc[4].x); acc[4].y = fmaf(a1.x, b.y, acc[4].y);
            acc[4].z = fmaf(a1.x, b.z, acc[4].z); acc[4].w = fmaf(a1.x, b.w, acc[4].w);
            acc[5].x = fmaf(a1.y, b.x, acc[5].x); acc[5].y = fmaf(a1.y, b.y, acc[5].y);
            acc[5].z = fmaf(a1.y, b.z, acc[5].z); acc[5].w = fmaf(a1.y, b.w, acc[5].w);
            acc[6].x = fmaf(a1.z, b.x, acc[6].x); acc[6].y = fmaf(a1.z, b.y, acc[6].y);
            acc[6].z = fmaf(a1.z, b.z, acc[6].z); acc[6].w = fmaf(a1.z, b.w, acc[6].w);
            acc[7].x = fmaf(a1.w, b.x, acc[7].x); acc[7].y = fmaf(a1.w, b.y, acc[7].y);
            acc[7].z = fmaf(a1.w, b.z, acc[7].z); acc[7].w = fmaf(a1.w, b.w, acc[7].w);
        }
        __syncthreads();
    }

#pragma unroll
    for (int j = 0; j < 8; j++) {
        const int v = row0 + ty * 8 + j;
        if (v < n) {
            const float dv = dis[v];
            ushort4 r;
            r.x = f2bf(acc[j].x * dv);
            r.y = f2bf(acc[j].y * dv);
            r.z = f2bf(acc[j].z * dv);
            r.w = f2bf(acc[j].w * dv);
            *(ushort4*)&outb[(long)v * HID + tx * 4] = r;
        }
    }
}

// ---------------- gather aggregation + finalize (+ optional fused pool) ----------------
// One 64-lane wave per dst node; lane l covers cols 2l, 2l+1 (one bf16x2 = 4B per row).
// Index prefetch: lane-parallel csr_src load + __shfl broadcast, 4-way unrolled gathers.
template <bool POOL>
__global__ __launch_bounds__(256) void agg_kernel(const unsigned short* __restrict__ hsb,
                                                  const int* __restrict__ csr_src,
                                                  const int* __restrict__ row,
                                                  const float* __restrict__ dis,
                                                  const float* __restrict__ bias,
                                                  const int* __restrict__ batch,
                                                  float* __restrict__ out,
                                                  float* __restrict__ sums,
                                                  int* __restrict__ cnt, int n) {
    const int v = blockIdx.x * 4 + (threadIdx.x >> 6);
    if (v >= n) return;
    const int lane = threadIdx.x & 63;
    const int c = lane << 1;

    const int rs = row[v];
    const int re = row[v + 1];
    float ax0 = 0.f, ay0 = 0.f, ax1 = 0.f, ay1 = 0.f;

    for (int base = rs; base < re; base += 64) {
        int m = re - base;
        if (m > 64) m = 64;
        const int idx = (base + lane < re) ? csr_src[base + lane] : 0;
        int j = 0;
        for (; j + 4 <= m; j += 4) {
            const int s0 = __shfl(idx, j);
            const int s1 = __shfl(idx, j + 1);
            const int s2 = __shfl(idx, j + 2);
            const int s3 = __shfl(idx, j + 3);
            const unsigned int m0 = *(const unsigned int*)&hsb[(long)s0 * HID + c];
            const unsigned int m1 = *(const unsigned int*)&hsb[(long)s1 * HID + c];
            const unsigned int m2 = *(const unsigned int*)&hsb[(long)s2 * HID + c];
            const unsigned int m3 = *(const unsigned int*)&hsb[(long)s3 * HID + c];
            ax0 += bf2f(m0 & 0xffffu); ay0 += bf2f(m0 >> 16);
            ax1 += bf2f(m1 & 0xffffu); ay1 += bf2f(m1 >> 16);
            ax0 += bf2f(m2 & 0xffffu); ay0 += bf2f(m2 >> 16);
            ax1 += bf2f(m3 & 0xffffu); ay1 += bf2f(m3 >> 16);
        }
        for (; j < m; j++) {
            const int s = __shfl(idx, j);
            const unsigned int mm = *(const unsigned int*)&hsb[(long)s * HID + c];
            ax0 += bf2f(mm & 0xffffu); ay0 += bf2f(mm >> 16);
        }
    }

    const unsigned int selfm = *(const unsigned int*)&hsb[(long)v * HID + c];
    const float sx = ax0 + ax1 + bf2f(selfm & 0xffffu);
    const float sy = ay0 + ay1 + bf2f(selfm >> 16);
    const float dv = dis[v];
    const float rx = fmaxf(fmaf(dv, sx, bias[c]), 0.f);
    const float ry = fmaxf(fmaf(dv, sy, bias[c + 1]), 0.f);
    if (POOL) {
        const int g = batch[v];
        unsafeAtomicAdd(&sums[g * HID + c], rx);
        unsafeAtomicAdd(&sums[g * HID + c + 1], ry);
        if (lane == 0) atomicAdd(&cnt[g], 1);
    } else {
        float2 r; r.x = rx; r.y = ry;
        *(float2*)&out[(long)v * HID + c] = r;
    }
}

// ---------------- mean + MLP head ----------------
__global__ __launch_bounds__(64) void mlp_kernel(const float* __restrict__ sums,
                                                 const int* __restrict__ cnt,
                                                 const float* __restrict__ Wl1,
                                                 const float* __restrict__ bl1,
                                                 const float* __restrict__ Wl2,
                                                 const float* __restrict__ bl2,
                                                 float* __restrict__ out) {
    const int g = blockIdx.x, t = threadIdx.x;
    __shared__ float mean[HID];
    __shared__ float hid[64];
    const float c = fmaxf((float)cnt[g], 1.0f);
    mean[t] = sums[g * HID + t] / c;
    mean[t + 64] = sums[g * HID + 64 + t] / c;
    __syncthreads();
    float acc = bl1[t];
#pragma unroll 4
    for (int k = 0; k < HID; k++) acc = fmaf(mean[k], Wl1[k * 64 + t], acc);
    hid[t] = fmaxf(acc, 0.f);
    __syncthreads();
    if (t < 5) {
        float a = bl2[t];
#pragma unroll 4
        for (int k = 0; k < 64; k++) a = fmaf(hid[k], Wl2[k * 5 + t], a);
        out[g * 5 + t] = 1.f / (1.f + expf(-a));
    }
}

extern "C" void kernel_launch(void* const* d_in, const int* in_sizes, int n_in,
                              void* d_out, int out_size, void* d_ws, size_t ws_size,
                              hipStream_t stream) {
    const float* x   = (const float*)d_in[0];
    const int* ei    = (const int*)d_in[1];
    const int* batch = (const int*)d_in[2];
    const float* W1  = (const float*)d_in[3];
    const float* b1  = (const float*)d_in[4];
    const float* W2  = (const float*)d_in[5];
    const float* b2  = (const float*)d_in[6];
    const float* Wl1 = (const float*)d_in[7];
    const float* bl1 = (const float*)d_in[8];
    const float* Wl2 = (const float*)d_in[9];
    const float* bl2 = (const float*)d_in[10];
    float* out = (float*)d_out;

    const int n = in_sizes[0] / IN_DIM;       // 50000
    const int E = in_sizes[1] / 2;            // 1600000
    const int* src = ei;
    const int* dst = ei + E;

    char* ws = (char*)d_ws;
    size_t off = 0;
    auto alloc = [&](size_t bytes) {
        void* p = ws + off;
        off = (off + bytes + 255) & ~(size_t)255;
        return p;
    };
    int*   deg       = (int*)alloc((size_t)n * 4);
    float* dis       = (float*)alloc((size_t)n * 4);
    int*   row       = (int*)alloc((size_t)(n + 1) * 4);
    int*   cursor    = (int*)alloc((size_t)n * 4);
    int*   csr_src   = (int*)alloc((size_t)E * 4);
    int*   blockSums = (int*)alloc(256 * 4);
    unsigned short* hsb = (unsigned short*)alloc((size_t)n * HID * 2);  // bf16 messages
    float* buf1 = (float*)alloc((size_t)n * HID * 4);                    // fp32 inter-layer h
    float* sums = (float*)alloc((size_t)NGRAPH * HID * 4);
    int*   cnt  = (int*)alloc((size_t)NGRAPH * 4);
    (void)ws_size;

    const int nb = (n + 1023) / 1024;
    const int gemmBlocks = (n + 63) / 64;
    const int aggBlocks  = (n + 3) / 4;

    // --- degree / norm / CSR ---
    hipMemsetAsync(deg, 0, (size_t)n * 4, stream);
    deg_kernel<<<(E + 255) / 256, 256, 0, stream>>>(dst, deg, E);
    dis_kernel<<<(n + 255) / 256, 256, 0, stream>>>(deg, dis, n);
    scan_part<<<nb, 256, 0, stream>>>(deg, row, blockSums, n);
    scan_tops<<<1, 64, 0, stream>>>(blockSums, nb);
    scan_add<<<nb, 256, 0, stream>>>(row, cursor, blockSums, n, E);
    fill_kernel<<<(E + 255) / 256, 256, 0, stream>>>(src, dst, cursor, csr_src, E);

    // --- conv1 ---
    gemm_tile<IN_DIM><<<gemmBlocks, 256, 0, stream>>>(x, W1, dis, hsb, n);
    agg_kernel<false><<<aggBlocks, 256, 0, stream>>>(hsb, csr_src, row, dis, b1, batch,
                                                     buf1, nullptr, nullptr, n);

    // --- conv2 (pool fused) ---
    gemm_tile<HID><<<gemmBlocks, 256, 0, stream>>>(buf1, W2, dis, hsb, n);
    hipMemsetAsync(sums, 0, (size_t)NGRAPH * HID * 4, stream);
    hipMemsetAsync(cnt, 0, (size_t)NGRAPH * 4, stream);
    agg_kernel<true><<<aggBlocks, 256, 0, stream>>>(hsb, csr_src, row, dis, b2, batch,
                                                    nullptr, sums, cnt, n);

    // --- head ---
    mlp_kernel<<<NGRAPH, 64, 0, stream>>>(sums, cnt, Wl1, bl1, Wl2, bl2, out);
}